// Round 7
// baseline (164.395 us; speedup 1.0000x reference)
//
#include <hip/hip_runtime.h>

#define T_SEQ   2048
#define EMBD    768
#define N_HEAD  12
#define HDIM    64
#define BATCH   2

typedef float f32x4 __attribute__((ext_vector_type(4)));
typedef short bf16x8 __attribute__((ext_vector_type(8)));
typedef unsigned short u16;
typedef unsigned int u32;
typedef u16 u16x4 __attribute__((ext_vector_type(4)));

#define MFMA_BF16(a, b, c) __builtin_amdgcn_mfma_f32_16x16x32_bf16((a), (b), (c), 0, 0, 0)

__device__ __forceinline__ u16 f2bf(float f) {
    union { float f; unsigned u; } v; v.f = f;
    unsigned r = v.u + 0x7fffu + ((v.u >> 16) & 1u);
    return (u16)(r >> 16);
}

// pack two fp32 -> two bf16 (truncating) in ONE v_perm_b32: [bf(hi):bf(lo)]
__device__ __forceinline__ u32 pack2(float hi, float lo) {
    union { float f; u32 u; } a, b;
    a.f = hi; b.f = lo;
    return __builtin_amdgcn_perm(a.u, b.u, 0x07060302u);
}

// async global->LDS DMA, 16 B per lane; LDS dest = wave-uniform base + lane*16
__device__ __forceinline__ void gload_lds16(const u16* g, u16* l) {
    __builtin_amdgcn_global_load_lds(
        (const __attribute__((address_space(1))) u32*)g,
        (__attribute__((address_space(3))) u32*)l, 16, 0, 0);
}

// ---------------------------------------------------------------------------
// Fused prep: x fp32->bf16 (blocks 0..1535), w_qkv transpose (1536..3263),
// w_proj transpose (3264..3839).
// ---------------------------------------------------------------------------
__global__ __launch_bounds__(256) void prep_kernel(
    const float* __restrict__ x, const float* __restrict__ wq,
    const float* __restrict__ wp, u16* __restrict__ xb,
    u16* __restrict__ wqT, u16* __restrict__ wpT)
{
    const int bid = blockIdx.x;
    const int tid = threadIdx.x;
    if (bid < 1536) {
        const int i = bid * 2048 + tid * 8;
        const float4 f0 = *(const float4*)&x[i];
        const float4 f1 = *(const float4*)&x[i + 4];
        bf16x8 r;
        r[0] = (short)f2bf(f0.x); r[1] = (short)f2bf(f0.y);
        r[2] = (short)f2bf(f0.z); r[3] = (short)f2bf(f0.w);
        r[4] = (short)f2bf(f1.x); r[5] = (short)f2bf(f1.y);
        r[6] = (short)f2bf(f1.z); r[7] = (short)f2bf(f1.w);
        *(bf16x8*)&xb[i] = r;
        return;
    }
    __shared__ float tile[32][33];
    const float* W; u16* Wt; int N, t;
    if (bid < 3264) { W = wq; Wt = wqT; N = 2304; t = bid - 1536; }
    else            { W = wp; Wt = wpT; N = 768;  t = bid - 3264; }
    const int ntiles = N / 32;
    const int n0 = (t % ntiles) * 32;
    const int k0 = (t / ntiles) * 32;
    const int c  = tid & 31;
    const int r8 = tid >> 5;
#pragma unroll
    for (int rr = r8; rr < 32; rr += 8)
        tile[rr][c] = W[(size_t)(k0 + rr) * N + n0 + c];
    __syncthreads();
#pragma unroll
    for (int rr = r8; rr < 32; rr += 8)
        Wt[(size_t)(n0 + rr) * 768 + k0 + c] = f2bf(tile[c][rr]);
}

// ---------------------------------------------------------------------------
// m97-style bf16 MFMA GEMM: A [M x 768] @ Bt^T, Bt pre-transposed [N x 768].
// TM x 128 tile (TM=128 or 64), 4 waves 2x2 (wave tile (TM/2) x 64), BK=64.
// global_load_lds width-16 staging, XOR chunk swizzle slot = c ^ (row&7).
// (256,3): cap regs ~170 so 3 blocks/CU resident (R6 used (256,2) and likely
// sat at 2 waves/SIMD). Per-ks frag loads keep live frags at 32 regs.
// SCATTER=1: bf16 Q (pre-scaled 0.125*log2e) / K [b,h,t,d], V^T [b,h,d,t].
// SCATTER=0: fp32 C [M x NCOLS].
// ---------------------------------------------------------------------------
template <int NCOLS, int SCATTER, int TM>
__global__ __launch_bounds__(256, 3) void mfma_gemm(
    const u16* __restrict__ A, const u16* __restrict__ Bt,
    float* __restrict__ C, u16* __restrict__ Qo, u16* __restrict__ Ko,
    u16* __restrict__ Vo)
{
    constexpr int MT = TM / 32;          // m-subtiles (16 rows) per wave
    constexpr int AI = TM / 32;          // A DMA issues per wave
    __shared__ u16 As[TM * 64];
    __shared__ u16 Bs[128 * 64];
    const int tid  = threadIdx.x;
    const int lane = tid & 63, wave = tid >> 6;
    const int l15  = lane & 15, quad = lane >> 4;
    const int wy   = wave >> 1, wx = wave & 1;
    const int row0 = blockIdx.y * TM, col0 = blockIdx.x * 128;

    // DMA mapping: lane fetches global chunk g = sc ^ sr so LDS slot (r,c)
    // holds global chunk c ^ (r&7)  (8 rows per issue, 16 B per lane).
    const int sr = lane >> 3;              // 0..7
    const int sc = lane & 7;               // 0..7 LDS slot
    const int g  = sc ^ sr;                // global k-chunk
    const u16* gA[AI]; const u16* gB[4]; u16* lA[AI]; u16* lB[4];
#pragma unroll
    for (int i = 0; i < AI; ++i) {
        const int rb = (i * 4 + wave) * 8;
        gA[i] = &A[(size_t)(row0 + rb + sr) * 768 + g * 8];
        lA[i] = &As[rb * 64];
    }
#pragma unroll
    for (int i = 0; i < 4; ++i) {
        const int rb = (i * 4 + wave) * 8;
        gB[i] = &Bt[(size_t)(col0 + rb + sr) * 768 + g * 8];
        lB[i] = &Bs[rb * 64];
    }

    f32x4 acc[MT][4];
#pragma unroll
    for (int i = 0; i < MT; ++i)
#pragma unroll
        for (int j = 0; j < 4; ++j) acc[i][j] = (f32x4){0.f, 0.f, 0.f, 0.f};

    for (int k0 = 0; k0 < 768; k0 += 64) {
        __syncthreads();                   // previous tile fully consumed
#pragma unroll
        for (int i = 0; i < AI; ++i) gload_lds16(gA[i] + k0, lA[i]);
#pragma unroll
        for (int i = 0; i < 4; ++i) gload_lds16(gB[i] + k0, lB[i]);
        __syncthreads();                   // DMA landed
#pragma unroll
        for (int ks = 0; ks < 2; ++ks) {
            bf16x8 af[MT], bfr[4];
#pragma unroll
            for (int mt = 0; mt < MT; ++mt)
                af[mt] = *(const bf16x8*)&As[(wy * (TM / 2) + mt * 16 + l15) * 64 +
                                             (((ks * 4 + quad) ^ (l15 & 7)) * 8)];
#pragma unroll
            for (int nt = 0; nt < 4; ++nt)
                bfr[nt] = *(const bf16x8*)&Bs[(wx * 64 + nt * 16 + l15) * 64 +
                                              (((ks * 4 + quad) ^ (l15 & 7)) * 8)];
#pragma unroll
            for (int mt = 0; mt < MT; ++mt)
#pragma unroll
                for (int nt = 0; nt < 4; ++nt)
                    acc[mt][nt] = MFMA_BF16(af[mt], bfr[nt], acc[mt][nt]);
        }
    }

    // epilogue: C-layout row=(quad*4+r), col=l15 within each 16x16 tile
    const float qscale = 0.18033688f;   // 0.125 * log2(e), folded into Q
#pragma unroll
    for (int mt = 0; mt < MT; ++mt) {
#pragma unroll
        for (int nt = 0; nt < 4; ++nt) {
            const int col = col0 + wx * 64 + nt * 16 + l15;
            if (SCATTER) {
                const int which = col / 768;
                const int hh = (col - which * 768) >> 6;
                const int dd = col & 63;
                if (which == 2) {
                    const int row = row0 + wy * (TM / 2) + mt * 16 + quad * 4;
                    const int bb = row >> 11, t0 = row & 2047;
                    u16x4 pk;
#pragma unroll
                    for (int r = 0; r < 4; ++r) pk[r] = f2bf(acc[mt][nt][r]);
                    *(u16x4*)&Vo[((size_t)(bb * N_HEAD + hh) * HDIM + dd) * T_SEQ + t0] = pk;
                } else {
                    u16* dst = (which == 0) ? Qo : Ko;
                    const float sc2 = (which == 0) ? qscale : 1.0f;
                    const size_t hb = (size_t)hh * T_SEQ * HDIM + dd;
#pragma unroll
                    for (int r = 0; r < 4; ++r) {
                        const int row = row0 + wy * (TM / 2) + mt * 16 + quad * 4 + r;
                        const int bb = row >> 11, tt = row & 2047;
                        dst[(size_t)bb * N_HEAD * T_SEQ * HDIM + hb + (size_t)tt * HDIM] =
                            f2bf(acc[mt][nt][r] * sc2);
                    }
                }
            } else {
#pragma unroll
                for (int r = 0; r < 4; ++r) {
                    const int row = row0 + wy * (TM / 2) + mt * 16 + quad * 4 + r;
                    C[(size_t)row * NCOLS + col] = acc[mt][nt][r];
                }
            }
        }
    }
}

// ---------------------------------------------------------------------------
// MFMA flash attention — R6 structure + K software-pipeline.
// Block = 4 waves: waves 0,1 -> q-tile 63-p (even/odd k64 tiles);
//                  waves 2,3 -> q-tile p. Constant work per block.
// S-MFMA split into i=0,1 / i=2,3 halves (shorter s lifetime); next tile's
// K fragments issued the moment the current ones are consumed, so the next
// iteration's S never waits on L2. V ks-halves loaded just-in-time.
// Q pre-scaled by 0.125*log2e -> exp2f. (256,3): (256,4) spilled (R4).
// ---------------------------------------------------------------------------
__global__ __launch_bounds__(256, 3) void attn_mfma(
    const u16* __restrict__ Q, const u16* __restrict__ K,
    const u16* __restrict__ Vt, u16* __restrict__ Aout)
{
    __shared__ float Comb[5120];              // 20480 B, aliased as Ps
    u16* PsAll = (u16*)Comb;

    const int tid  = threadIdx.x;
    const int lane = tid & 63, wave = tid >> 6;
    const int l15  = lane & 15, quad = lane >> 4;

    // XCD swizzle: blocks with same (idx%8) share an XCD -> same bh group
    const int f    = blockIdx.x;              // 0..767
    const int slot = f >> 3;                  // 0..95
    const int bh   = (f & 7) * 3 + (slot >> 5);
    const int p    = slot & 31;
    const int b    = bh / N_HEAD, h = bh - b * N_HEAD;

    const int j      = (wave < 2) ? (63 - p) : p;   // heavy pair on waves 0,1
    const int parity = wave & 1;
    const int qb     = j * 32;
    const int nk     = (j >> 1) + 1;          // 64-wide k-tiles
    const size_t base = (size_t)bh * T_SEQ * HDIM;

    // Q fragments (B-operand: n=q=l15, k=d)
    bf16x8 qf[2][2];
#pragma unroll
    for (int jq = 0; jq < 2; ++jq)
#pragma unroll
        for (int ks = 0; ks < 2; ++ks)
            qf[jq][ks] = *(const bf16x8*)&Q[base + (size_t)(qb + jq * 16 + l15) * HDIM +
                                            ks * 32 + quad * 8];

    f32x4 o[2][4], l_acc[2];
#pragma unroll
    for (int jq = 0; jq < 2; ++jq) {
        l_acc[jq] = (f32x4){0.f, 0.f, 0.f, 0.f};
#pragma unroll
        for (int nt = 0; nt < 4; ++nt) o[jq][nt] = (f32x4){0.f, 0.f, 0.f, 0.f};
    }

    bf16x8 onesf;
#pragma unroll
    for (int u = 0; u < 8; ++u) onesf[u] = (short)0x3F80;  // bf16 1.0

    u16* myPs = PsAll + wave * 2304;          // [32 q][72 key-stride]

    // initial K fragments (A-operand: m=key=l15, k=d)
    bf16x8 kc[4][2];
    {
        const int k0 = parity * 64;
#pragma unroll
        for (int i = 0; i < 4; ++i)
#pragma unroll
            for (int ks = 0; ks < 2; ++ks)
                kc[i][ks] = *(const bf16x8*)&K[base + (size_t)(k0 + i * 16 + l15) * HDIM +
                                               ks * 32 + quad * 8];
    }

    for (int kt = parity; kt < nk; kt += 2) {
        const int k0 = kt * 64;
        const bool pf = (kt + 2 < nk);

        // S^T rows i=0,1 (keys k0..k0+31)
        f32x4 s[4][2];
#pragma unroll
        for (int i = 0; i < 4; ++i)
#pragma unroll
            for (int jq = 0; jq < 2; ++jq) s[i][jq] = (f32x4){0.f, 0.f, 0.f, 0.f};
#pragma unroll
        for (int ks = 0; ks < 2; ++ks)
#pragma unroll
            for (int i = 0; i < 2; ++i)
#pragma unroll
                for (int jq = 0; jq < 2; ++jq)
                    s[i][jq] = MFMA_BF16(kc[i][ks], qf[jq][ks], s[i][jq]);

        // V ks=0 fragments (B-operand: n=d=l15, k=key)
        bf16x8 vf0[4];
#pragma unroll
        for (int nt = 0; nt < 4; ++nt)
            vf0[nt] = *(const bf16x8*)&Vt[base + (size_t)(nt * 16 + l15) * T_SEQ +
                                          k0 + quad * 8];

        // exp2 + mask + pack, i=0,1
#pragma unroll
        for (int i = 0; i < 2; ++i)
#pragma unroll
            for (int jq = 0; jq < 2; ++jq) {
                float pv[4];
                if (k0 + i * 16 + 15 > qb + jq * 16) {
                    const int q = qb + jq * 16 + l15;
#pragma unroll
                    for (int r = 0; r < 4; ++r) {
                        const int key = k0 + i * 16 + quad * 4 + r;
                        pv[r] = exp2f((key > q) ? -1e30f : s[i][jq][r]);
                    }
                } else {
#pragma unroll
                    for (int r = 0; r < 4; ++r) pv[r] = exp2f(s[i][jq][r]);
                }
                uint2 w;
                w.x = pack2(pv[1], pv[0]);
                w.y = pack2(pv[3], pv[2]);
                *(uint2*)&myPs[(jq * 16 + l15) * 72 + i * 16 + quad * 4] = w;
            }

        // S^T rows i=2,3 (keys k0+32..k0+63) — consumes the rest of kc
#pragma unroll
        for (int ks = 0; ks < 2; ++ks)
#pragma unroll
            for (int i = 2; i < 4; ++i)
#pragma unroll
                for (int jq = 0; jq < 2; ++jq)
                    s[i][jq] = MFMA_BF16(kc[i][ks], qf[jq][ks], s[i][jq]);

        // prefetch next K tile (kc dead) — covers exp/PV below
        if (pf) {
            const int kn0 = k0 + 128;
#pragma unroll
            for (int i = 0; i < 4; ++i)
#pragma unroll
                for (int ks = 0; ks < 2; ++ks)
                    kc[i][ks] = *(const bf16x8*)&K[base +
                        (size_t)(kn0 + i * 16 + l15) * HDIM + ks * 32 + quad * 8];
        }

        // pa ks=0 (keys 0..31, already stored)
        bf16x8 pa0[2];
#pragma unroll
        for (int jq = 0; jq < 2; ++jq)
            pa0[jq] = *(const bf16x8*)&myPs[(jq * 16 + l15) * 72 + quad * 8];

        // exp2 + mask + pack, i=2,3
#pragma unroll
        for (int i = 2; i < 4; ++i)
#pragma unroll
            for (int jq = 0; jq < 2; ++jq) {
                float pv[4];
                if (k0 + i * 16 + 15 > qb + jq * 16) {
                    const int q = qb + jq * 16 + l15;
#pragma unroll
                    for (int r = 0; r < 4; ++r) {
                        const int key = k0 + i * 16 + quad * 4 + r;
                        pv[r] = exp2f((key > q) ? -1e30f : s[i][jq][r]);
                    }
                } else {
#pragma unroll
                    for (int r = 0; r < 4; ++r) pv[r] = exp2f(s[i][jq][r]);
                }
                uint2 w;
                w.x = pack2(pv[1], pv[0]);
                w.y = pack2(pv[3], pv[2]);
                *(uint2*)&myPs[(jq * 16 + l15) * 72 + i * 16 + quad * 4] = w;
            }

        // O += P V (ks=0) ; l += P . 1
#pragma unroll
        for (int jq = 0; jq < 2; ++jq) {
#pragma unroll
            for (int nt = 0; nt < 4; ++nt)
                o[jq][nt] = MFMA_BF16(pa0[jq], vf0[nt], o[jq][nt]);
            l_acc[jq] = MFMA_BF16(pa0[jq], onesf, l_acc[jq]);
        }

        // V ks=1 + pa ks=1 + PV (ks=1)
        bf16x8 vf1[4];
#pragma unroll
        for (int nt = 0; nt < 4; ++nt)
            vf1[nt] = *(const bf16x8*)&Vt[base + (size_t)(nt * 16 + l15) * T_SEQ +
                                          k0 + 32 + quad * 8];
        bf16x8 pa1[2];
#pragma unroll
        for (int jq = 0; jq < 2; ++jq)
            pa1[jq] = *(const bf16x8*)&myPs[(jq * 16 + l15) * 72 + 32 + quad * 8];
#pragma unroll
        for (int jq = 0; jq < 2; ++jq) {
#pragma unroll
            for (int nt = 0; nt < 4; ++nt)
                o[jq][nt] = MFMA_BF16(pa1[jq], vf1[nt], o[jq][nt]);
            l_acc[jq] = MFMA_BF16(pa1[jq], onesf, l_acc[jq]);
        }
    }

    // ---- combine (Ps dead; Comb aliases it — barrier guards the alias) ----
    __syncthreads();
    if (parity == 1) {
        float* R = Comb + (wave >> 1) * 2560;
#pragma unroll
        for (int jq = 0; jq < 2; ++jq) {
#pragma unroll
            for (int nt = 0; nt < 4; ++nt)
#pragma unroll
                for (int r = 0; r < 4; ++r)
                    R[(jq * 16 + nt * 4 + r) * 64 + lane] = o[jq][nt][r];
#pragma unroll
            for (int r = 0; r < 4; ++r)
                R[(32 + jq * 4 + r) * 64 + lane] = l_acc[jq][r];
        }
    }
    __syncthreads();
    if (parity == 0) {
        const float* R = Comb + (wave >> 1) * 2560;
#pragma unroll
        for (int jq = 0; jq < 2; ++jq) {
#pragma unroll
            for (int nt = 0; nt < 4; ++nt)
#pragma unroll
                for (int r = 0; r < 4; ++r)
                    o[jq][nt][r] += R[(jq * 16 + nt * 4 + r) * 64 + lane];
#pragma unroll
            for (int r = 0; r < 4; ++r)
                l_acc[jq][r] += R[(32 + jq * 4 + r) * 64 + lane];
        }
#pragma unroll
        for (int jq = 0; jq < 2; ++jq) {
            f32x4 inv;
#pragma unroll
            for (int r = 0; r < 4; ++r) inv[r] = 1.0f / l_acc[jq][r];
#pragma unroll
            for (int nt = 0; nt < 4; ++nt) {
                const int d = nt * 16 + l15;
#pragma unroll
                for (int r = 0; r < 4; ++r) {
                    const int q = qb + jq * 16 + quad * 4 + r;
                    Aout[(size_t)(b * T_SEQ + q) * EMBD + h * HDIM + d] =
                        f2bf(o[jq][nt][r] * inv[r]);
                }
            }
        }
    }
}

// ---------------------------------------------------------------------------
extern "C" void kernel_launch(void* const* d_in, const int* in_sizes, int n_in,
                              void* d_out, int out_size, void* d_ws, size_t ws_size,
                              hipStream_t stream)
{
    (void)in_sizes; (void)n_in; (void)out_size; (void)ws_size;
    const float* x      = (const float*)d_in[0];
    const float* w_qkv  = (const float*)d_in[1];
    const float* w_proj = (const float*)d_in[2];
    float* out = (float*)d_out;

    u16* ws = (u16*)d_ws;
    const size_t NX  = (size_t)BATCH * T_SEQ * EMBD;          // 3,145,728
    const size_t NWQ = (size_t)EMBD * 3 * EMBD;               // 1,769,472
    const size_t NWP = (size_t)EMBD * EMBD;                   //   589,824
    const size_t SZ  = (size_t)BATCH * N_HEAD * T_SEQ * HDIM; // 3,145,728
    u16* xb     = ws;
    u16* wqkvT  = xb + NX;
    u16* wprojT = wqkvT + NWQ;
    u16* Qb     = wprojT + NWP;
    u16* Kb     = Qb + SZ;
    u16* Vtb    = Kb + SZ;   // V stored transposed [b,h,d,t]
    u16* Ab     = Vtb + SZ;

    dim3 blk(256);
    prep_kernel<<<dim3(3840), blk, 0, stream>>>(x, w_qkv, w_proj, xb, wqkvT, wprojT);

    // qkv: 18 x 32 = 576 blocks
    mfma_gemm<3 * EMBD, 1, 128><<<dim3(3 * EMBD / 128, BATCH * T_SEQ / 128), blk, 0, stream>>>(
        xb, wqkvT, nullptr, Qb, Kb, Vtb);

    attn_mfma<<<dim3(32 * N_HEAD * BATCH), blk, 0, stream>>>(Qb, Kb, Vtb, Ab);

    // proj: 6 x 64 = 384 blocks (TM=64 — R6's 128-row tile gave only 192)
    mfma_gemm<EMBD, 0, 64><<<dim3(EMBD / 128, BATCH * T_SEQ / 64), blk, 0, stream>>>(
        Ab, wprojT, out, nullptr, nullptr, nullptr);
}

// Round 8
// 158.384 us; speedup vs baseline: 1.0380x; 1.0380x over previous
//
#include <hip/hip_runtime.h>

#define T_SEQ   2048
#define EMBD    768
#define N_HEAD  12
#define HDIM    64
#define BATCH   2

typedef float f32x4 __attribute__((ext_vector_type(4)));
typedef short bf16x8 __attribute__((ext_vector_type(8)));
typedef unsigned short u16;
typedef unsigned int u32;
typedef u16 u16x4 __attribute__((ext_vector_type(4)));

#define MFMA_BF16(a, b, c) __builtin_amdgcn_mfma_f32_16x16x32_bf16((a), (b), (c), 0, 0, 0)

__device__ __forceinline__ u16 f2bf(float f) {
    union { float f; unsigned u; } v; v.f = f;
    unsigned r = v.u + 0x7fffu + ((v.u >> 16) & 1u);
    return (u16)(r >> 16);
}

// pack two fp32 -> two bf16 (truncating) in ONE v_perm_b32: [bf(hi):bf(lo)]
__device__ __forceinline__ u32 pack2(float hi, float lo) {
    union { float f; u32 u; } a, b;
    a.f = hi; b.f = lo;
    return __builtin_amdgcn_perm(a.u, b.u, 0x07060302u);
}

// async global->LDS DMA, 16 B per lane; LDS dest = wave-uniform base + lane*16
__device__ __forceinline__ void gload_lds16(const u16* g, u16* l) {
    __builtin_amdgcn_global_load_lds(
        (const __attribute__((address_space(1))) u32*)g,
        (__attribute__((address_space(3))) u32*)l, 16, 0, 0);
}

// ---------------------------------------------------------------------------
// Fused prep: x fp32->bf16 (blocks 0..1535), w_qkv transpose (1536..3263),
// w_proj transpose (3264..3839).
// ---------------------------------------------------------------------------
__global__ __launch_bounds__(256) void prep_kernel(
    const float* __restrict__ x, const float* __restrict__ wq,
    const float* __restrict__ wp, u16* __restrict__ xb,
    u16* __restrict__ wqT, u16* __restrict__ wpT)
{
    const int bid = blockIdx.x;
    const int tid = threadIdx.x;
    if (bid < 1536) {
        const int i = bid * 2048 + tid * 8;
        const float4 f0 = *(const float4*)&x[i];
        const float4 f1 = *(const float4*)&x[i + 4];
        bf16x8 r;
        r[0] = (short)f2bf(f0.x); r[1] = (short)f2bf(f0.y);
        r[2] = (short)f2bf(f0.z); r[3] = (short)f2bf(f0.w);
        r[4] = (short)f2bf(f1.x); r[5] = (short)f2bf(f1.y);
        r[6] = (short)f2bf(f1.z); r[7] = (short)f2bf(f1.w);
        *(bf16x8*)&xb[i] = r;
        return;
    }
    __shared__ float tile[32][33];
    const float* W; u16* Wt; int N, t;
    if (bid < 3264) { W = wq; Wt = wqT; N = 2304; t = bid - 1536; }
    else            { W = wp; Wt = wpT; N = 768;  t = bid - 3264; }
    const int ntiles = N / 32;
    const int n0 = (t % ntiles) * 32;
    const int k0 = (t / ntiles) * 32;
    const int c  = tid & 31;
    const int r8 = tid >> 5;
#pragma unroll
    for (int rr = r8; rr < 32; rr += 8)
        tile[rr][c] = W[(size_t)(k0 + rr) * N + n0 + c];
    __syncthreads();
#pragma unroll
    for (int rr = r8; rr < 32; rr += 8)
        Wt[(size_t)(n0 + rr) * 768 + k0 + c] = f2bf(tile[c][rr]);
}

// ---------------------------------------------------------------------------
// m97-style bf16 MFMA GEMM: A [M x 768] @ Bt^T, Bt pre-transposed [N x 768].
// TM x 128 tile (TM=128 or 64), 4 waves 2x2 (wave tile (TM/2) x 64), BK=64.
// global_load_lds width-16 staging, XOR chunk swizzle slot = c ^ (row&7).
// SCATTER=1: bf16 Q (pre-scaled 0.125*log2e) / K [b,h,t,d], V^T [b,h,d,t].
// SCATTER=0: fp32 C [M x NCOLS].
// ---------------------------------------------------------------------------
template <int NCOLS, int SCATTER, int TM>
__global__ __launch_bounds__(256, 3) void mfma_gemm(
    const u16* __restrict__ A, const u16* __restrict__ Bt,
    float* __restrict__ C, u16* __restrict__ Qo, u16* __restrict__ Ko,
    u16* __restrict__ Vo)
{
    constexpr int MT = TM / 32;          // m-subtiles (16 rows) per wave
    constexpr int AI = TM / 32;          // A DMA issues per wave
    __shared__ u16 As[TM * 64];
    __shared__ u16 Bs[128 * 64];
    const int tid  = threadIdx.x;
    const int lane = tid & 63, wave = tid >> 6;
    const int l15  = lane & 15, quad = lane >> 4;
    const int wy   = wave >> 1, wx = wave & 1;
    const int row0 = blockIdx.y * TM, col0 = blockIdx.x * 128;

    // DMA mapping: lane fetches global chunk g = sc ^ sr so LDS slot (r,c)
    // holds global chunk c ^ (r&7)  (8 rows per issue, 16 B per lane).
    const int sr = lane >> 3;              // 0..7
    const int sc = lane & 7;               // 0..7 LDS slot
    const int g  = sc ^ sr;                // global k-chunk
    const u16* gA[AI]; const u16* gB[4]; u16* lA[AI]; u16* lB[4];
#pragma unroll
    for (int i = 0; i < AI; ++i) {
        const int rb = (i * 4 + wave) * 8;
        gA[i] = &A[(size_t)(row0 + rb + sr) * 768 + g * 8];
        lA[i] = &As[rb * 64];
    }
#pragma unroll
    for (int i = 0; i < 4; ++i) {
        const int rb = (i * 4 + wave) * 8;
        gB[i] = &Bt[(size_t)(col0 + rb + sr) * 768 + g * 8];
        lB[i] = &Bs[rb * 64];
    }

    f32x4 acc[MT][4];
#pragma unroll
    for (int i = 0; i < MT; ++i)
#pragma unroll
        for (int j = 0; j < 4; ++j) acc[i][j] = (f32x4){0.f, 0.f, 0.f, 0.f};

    for (int k0 = 0; k0 < 768; k0 += 64) {
        __syncthreads();                   // previous tile fully consumed
#pragma unroll
        for (int i = 0; i < AI; ++i) gload_lds16(gA[i] + k0, lA[i]);
#pragma unroll
        for (int i = 0; i < 4; ++i) gload_lds16(gB[i] + k0, lB[i]);
        __syncthreads();                   // DMA landed
#pragma unroll
        for (int ks = 0; ks < 2; ++ks) {
            bf16x8 af[MT], bfr[4];
#pragma unroll
            for (int mt = 0; mt < MT; ++mt)
                af[mt] = *(const bf16x8*)&As[(wy * (TM / 2) + mt * 16 + l15) * 64 +
                                             (((ks * 4 + quad) ^ (l15 & 7)) * 8)];
#pragma unroll
            for (int nt = 0; nt < 4; ++nt)
                bfr[nt] = *(const bf16x8*)&Bs[(wx * 64 + nt * 16 + l15) * 64 +
                                              (((ks * 4 + quad) ^ (l15 & 7)) * 8)];
#pragma unroll
            for (int mt = 0; mt < MT; ++mt)
#pragma unroll
                for (int nt = 0; nt < 4; ++nt)
                    acc[mt][nt] = MFMA_BF16(af[mt], bfr[nt], acc[mt][nt]);
        }
    }

    // epilogue: C-layout row=(quad*4+r), col=l15 within each 16x16 tile
    const float qscale = 0.18033688f;   // 0.125 * log2(e), folded into Q
#pragma unroll
    for (int mt = 0; mt < MT; ++mt) {
#pragma unroll
        for (int nt = 0; nt < 4; ++nt) {
            const int col = col0 + wx * 64 + nt * 16 + l15;
            if (SCATTER) {
                const int which = col / 768;
                const int hh = (col - which * 768) >> 6;
                const int dd = col & 63;
                if (which == 2) {
                    const int row = row0 + wy * (TM / 2) + mt * 16 + quad * 4;
                    const int bb = row >> 11, t0 = row & 2047;
                    u16x4 pk;
#pragma unroll
                    for (int r = 0; r < 4; ++r) pk[r] = f2bf(acc[mt][nt][r]);
                    *(u16x4*)&Vo[((size_t)(bb * N_HEAD + hh) * HDIM + dd) * T_SEQ + t0] = pk;
                } else {
                    u16* dst = (which == 0) ? Qo : Ko;
                    const float sc2 = (which == 0) ? qscale : 1.0f;
                    const size_t hb = (size_t)hh * T_SEQ * HDIM + dd;
#pragma unroll
                    for (int r = 0; r < 4; ++r) {
                        const int row = row0 + wy * (TM / 2) + mt * 16 + quad * 4 + r;
                        const int bb = row >> 11, tt = row & 2047;
                        dst[(size_t)bb * N_HEAD * T_SEQ * HDIM + hb + (size_t)tt * HDIM] =
                            f2bf(acc[mt][nt][r] * sc2);
                    }
                }
            } else {
#pragma unroll
                for (int r = 0; r < 4; ++r) {
                    const int row = row0 + wy * (TM / 2) + mt * 16 + quad * 4 + r;
                    C[(size_t)row * NCOLS + col] = acc[mt][nt][r];
                }
            }
        }
    }
}

// ---------------------------------------------------------------------------
// MFMA flash attention — R6 body + SIMD load-balancing wave-role rotation.
// Previously waves 0,1 of EVERY block took the heavy q-tile (63-p) and waves
// 2,3 the light one (p); wave i maps to SIMD i, so SIMDs 0,1 hosted only
// heavy waves (serialized) while SIMDs 2,3 idled after their light waves
// finished. wsel = (wave + blockIdx) & 3 rotates roles per block so heavy
// waves spread across all 4 SIMDs. Pairs (wsel 0,1) and (wsel 2,3) stay on
// adjacent waves, so the combine logic is unchanged (keyed off wsel).
// No K-prefetch (R7: held regs across exp, regressed 55->59 us).
// (256,3): (256,4) forced 64 VGPR and spilled accumulators (R4).
// ---------------------------------------------------------------------------
__global__ __launch_bounds__(256, 3) void attn_mfma(
    const u16* __restrict__ Q, const u16* __restrict__ K,
    const u16* __restrict__ Vt, u16* __restrict__ Aout)
{
    __shared__ float Comb[5120];              // 20480 B, aliased as Ps
    u16* PsAll = (u16*)Comb;

    const int tid  = threadIdx.x;
    const int lane = tid & 63, wave = tid >> 6;
    const int l15  = lane & 15, quad = lane >> 4;

    // XCD swizzle: blocks with same (idx%8) share an XCD -> same bh group
    const int f    = blockIdx.x;              // 0..767
    const int slot = f >> 3;                  // 0..95
    const int bh   = (f & 7) * 3 + (slot >> 5);
    const int p    = slot & 31;
    const int b    = bh / N_HEAD, h = bh - b * N_HEAD;

    const int wsel   = (wave + f) & 3;        // rotated role
    const int j      = (wsel < 2) ? (63 - p) : p;
    const int parity = wsel & 1;
    const int qb     = j * 32;
    const int nk     = (j >> 1) + 1;          // 64-wide k-tiles
    const size_t base = (size_t)bh * T_SEQ * HDIM;

    // Q fragments (B-operand: n=q=l15, k=d)
    bf16x8 qf[2][2];
#pragma unroll
    for (int jq = 0; jq < 2; ++jq)
#pragma unroll
        for (int ks = 0; ks < 2; ++ks)
            qf[jq][ks] = *(const bf16x8*)&Q[base + (size_t)(qb + jq * 16 + l15) * HDIM +
                                            ks * 32 + quad * 8];

    f32x4 o[2][4], l_acc[2];
#pragma unroll
    for (int jq = 0; jq < 2; ++jq) {
        l_acc[jq] = (f32x4){0.f, 0.f, 0.f, 0.f};
#pragma unroll
        for (int nt = 0; nt < 4; ++nt) o[jq][nt] = (f32x4){0.f, 0.f, 0.f, 0.f};
    }

    bf16x8 onesf;
#pragma unroll
    for (int u = 0; u < 8; ++u) onesf[u] = (short)0x3F80;  // bf16 1.0

    u16* myPs = PsAll + wave * 2304;          // [32 q][72 key-stride]

    for (int kt = parity; kt < nk; kt += 2) {
        const int k0 = kt * 64;

        // S^T = K Q^T : rows=key, cols=q  (K frags direct from global)
        f32x4 s[4][2];
#pragma unroll
        for (int i = 0; i < 4; ++i)
#pragma unroll
            for (int jq = 0; jq < 2; ++jq) s[i][jq] = (f32x4){0.f, 0.f, 0.f, 0.f};
#pragma unroll
        for (int ks = 0; ks < 2; ++ks) {
            bf16x8 kf[4];  // A-operand: m=key=l15, k=d
#pragma unroll
            for (int i = 0; i < 4; ++i)
                kf[i] = *(const bf16x8*)&K[base + (size_t)(k0 + i * 16 + l15) * HDIM +
                                           ks * 32 + quad * 8];
#pragma unroll
            for (int i = 0; i < 4; ++i)
#pragma unroll
                for (int jq = 0; jq < 2; ++jq)
                    s[i][jq] = MFMA_BF16(kf[i], qf[jq][ks], s[i][jq]);
        }

        // V fragments (B-operand: n=d=l15, k=key) — latency hides behind exp
        bf16x8 vf[4][2];
#pragma unroll
        for (int nt = 0; nt < 4; ++nt)
#pragma unroll
            for (int ks = 0; ks < 2; ++ks)
                vf[nt][ks] = *(const bf16x8*)&Vt[base + (size_t)(nt * 16 + l15) * T_SEQ +
                                                 k0 + ks * 32 + quad * 8];

        // exp2 + mask + truncating bf16 pack, i=0,1 (keys k0..k0+31)
#pragma unroll
        for (int i = 0; i < 2; ++i)
#pragma unroll
            for (int jq = 0; jq < 2; ++jq) {
                float pv[4];
                if (k0 + i * 16 + 15 > qb + jq * 16) {       // uniform predicate
                    const int q = qb + jq * 16 + l15;
#pragma unroll
                    for (int r = 0; r < 4; ++r) {
                        const int key = k0 + i * 16 + quad * 4 + r;
                        pv[r] = exp2f((key > q) ? -1e30f : s[i][jq][r]);
                    }
                } else {
#pragma unroll
                    for (int r = 0; r < 4; ++r) pv[r] = exp2f(s[i][jq][r]);
                }
                uint2 w;
                w.x = pack2(pv[1], pv[0]);
                w.y = pack2(pv[3], pv[2]);
                *(uint2*)&myPs[(jq * 16 + l15) * 72 + i * 16 + quad * 4] = w;
            }

        // pa ks=0 (keys 0..31, just written) — LDS wait overlaps exp i=2,3
        bf16x8 pa0[2];
#pragma unroll
        for (int jq = 0; jq < 2; ++jq)
            pa0[jq] = *(const bf16x8*)&myPs[(jq * 16 + l15) * 72 + quad * 8];

        // exp2 + mask + pack, i=2,3 (keys k0+32..k0+63)
#pragma unroll
        for (int i = 2; i < 4; ++i)
#pragma unroll
            for (int jq = 0; jq < 2; ++jq) {
                float pv[4];
                if (k0 + i * 16 + 15 > qb + jq * 16) {
                    const int q = qb + jq * 16 + l15;
#pragma unroll
                    for (int r = 0; r < 4; ++r) {
                        const int key = k0 + i * 16 + quad * 4 + r;
                        pv[r] = exp2f((key > q) ? -1e30f : s[i][jq][r]);
                    }
                } else {
#pragma unroll
                    for (int r = 0; r < 4; ++r) pv[r] = exp2f(s[i][jq][r]);
                }
                uint2 w;
                w.x = pack2(pv[1], pv[0]);
                w.y = pack2(pv[3], pv[2]);
                *(uint2*)&myPs[(jq * 16 + l15) * 72 + i * 16 + quad * 4] = w;
            }

        // O += P V (ks=0) ; l += P . 1
#pragma unroll
        for (int jq = 0; jq < 2; ++jq) {
#pragma unroll
            for (int nt = 0; nt < 4; ++nt)
                o[jq][nt] = MFMA_BF16(pa0[jq], vf[nt][0], o[jq][nt]);
            l_acc[jq] = MFMA_BF16(pa0[jq], onesf, l_acc[jq]);
        }

        // pa ks=1 + PV (ks=1)
        bf16x8 pa1[2];
#pragma unroll
        for (int jq = 0; jq < 2; ++jq)
            pa1[jq] = *(const bf16x8*)&myPs[(jq * 16 + l15) * 72 + 32 + quad * 8];
#pragma unroll
        for (int jq = 0; jq < 2; ++jq) {
#pragma unroll
            for (int nt = 0; nt < 4; ++nt)
                o[jq][nt] = MFMA_BF16(pa1[jq], vf[nt][1], o[jq][nt]);
            l_acc[jq] = MFMA_BF16(pa1[jq], onesf, l_acc[jq]);
        }
    }

    // ---- combine (Ps dead; Comb aliases it — barrier guards the alias) ----
    __syncthreads();
    if (parity == 1) {
        float* R = Comb + (wsel >> 1) * 2560;
#pragma unroll
        for (int jq = 0; jq < 2; ++jq) {
#pragma unroll
            for (int nt = 0; nt < 4; ++nt)
#pragma unroll
                for (int r = 0; r < 4; ++r)
                    R[(jq * 16 + nt * 4 + r) * 64 + lane] = o[jq][nt][r];
#pragma unroll
            for (int r = 0; r < 4; ++r)
                R[(32 + jq * 4 + r) * 64 + lane] = l_acc[jq][r];
        }
    }
    __syncthreads();
    if (parity == 0) {
        const float* R = Comb + (wsel >> 1) * 2560;
#pragma unroll
        for (int jq = 0; jq < 2; ++jq) {
#pragma unroll
            for (int nt = 0; nt < 4; ++nt)
#pragma unroll
                for (int r = 0; r < 4; ++r)
                    o[jq][nt][r] += R[(jq * 16 + nt * 4 + r) * 64 + lane];
#pragma unroll
            for (int r = 0; r < 4; ++r)
                l_acc[jq][r] += R[(32 + jq * 4 + r) * 64 + lane];
        }
#pragma unroll
        for (int jq = 0; jq < 2; ++jq) {
            f32x4 inv;
#pragma unroll
            for (int r = 0; r < 4; ++r) inv[r] = 1.0f / l_acc[jq][r];
#pragma unroll
            for (int nt = 0; nt < 4; ++nt) {
                const int d = nt * 16 + l15;
#pragma unroll
                for (int r = 0; r < 4; ++r) {
                    const int q = qb + jq * 16 + quad * 4 + r;
                    Aout[(size_t)(b * T_SEQ + q) * EMBD + h * HDIM + d] =
                        f2bf(o[jq][nt][r] * inv[r]);
                }
            }
        }
    }
}

// ---------------------------------------------------------------------------
extern "C" void kernel_launch(void* const* d_in, const int* in_sizes, int n_in,
                              void* d_out, int out_size, void* d_ws, size_t ws_size,
                              hipStream_t stream)
{
    (void)in_sizes; (void)n_in; (void)out_size; (void)ws_size;
    const float* x      = (const float*)d_in[0];
    const float* w_qkv  = (const float*)d_in[1];
    const float* w_proj = (const float*)d_in[2];
    float* out = (float*)d_out;

    u16* ws = (u16*)d_ws;
    const size_t NX  = (size_t)BATCH * T_SEQ * EMBD;          // 3,145,728
    const size_t NWQ = (size_t)EMBD * 3 * EMBD;               // 1,769,472
    const size_t NWP = (size_t)EMBD * EMBD;                   //   589,824
    const size_t SZ  = (size_t)BATCH * N_HEAD * T_SEQ * HDIM; // 3,145,728
    u16* xb     = ws;
    u16* wqkvT  = xb + NX;
    u16* wprojT = wqkvT + NWQ;
    u16* Qb     = wprojT + NWP;
    u16* Kb     = Qb + SZ;
    u16* Vtb    = Kb + SZ;   // V stored transposed [b,h,d,t]
    u16* Ab     = Vtb + SZ;

    dim3 blk(256);
    prep_kernel<<<dim3(3840), blk, 0, stream>>>(x, w_qkv, w_proj, xb, wqkvT, wprojT);

    // qkv: 18 x 32 = 576 blocks
    mfma_gemm<3 * EMBD, 1, 128><<<dim3(3 * EMBD / 128, BATCH * T_SEQ / 128), blk, 0, stream>>>(
        xb, wqkvT, nullptr, Qb, Kb, Vtb);

    attn_mfma<<<dim3(32 * N_HEAD * BATCH), blk, 0, stream>>>(Qb, Kb, Vtb, Ab);

    // proj: 6 x 64 = 384 blocks
    mfma_gemm<EMBD, 0, 64><<<dim3(EMBD / 128, BATCH * T_SEQ / 64), blk, 0, stream>>>(
        Ab, wprojT, out, nullptr, nullptr, nullptr);
}